// Round 5
// baseline (760.085 us; speedup 1.0000x reference)
//
#include <hip/hip_runtime.h>
#include <math.h>

#define N_NODES 50000
#define N_GRAPHS 64
#define HID 128
#define SCAN_B 196  // ceil(50000/256)
#define NPB 128     // nodes per gather block (32 per wave)

typedef _Float16 half8 __attribute__((ext_vector_type(8)));
typedef float f32x4 __attribute__((ext_vector_type(4)));

__device__ __forceinline__ float lrelu(float e) { return e > 0.f ? e : 0.2f * e; }

// ---------------- CSR build ----------------
__global__ void count_kernel(const int* __restrict__ dst, int n_e, int* __restrict__ counts) {
    int e = blockIdx.x * blockDim.x + threadIdx.x;
    if (e < n_e) atomicAdd(&counts[dst[e]], 1);
}

__global__ __launch_bounds__(256) void block_reduce(const int* __restrict__ counts,
                                                    int* __restrict__ bsum) {
    __shared__ int red[256];
    int t = threadIdx.x;
    int i = blockIdx.x * 256 + t;
    red[t] = (i < N_NODES) ? counts[i] : 0;
    __syncthreads();
#pragma unroll
    for (int off = 128; off; off >>= 1) {
        if (t < off) red[t] += red[t + off];
        __syncthreads();
    }
    if (t == 0) bsum[blockIdx.x] = red[0];
}

__global__ __launch_bounds__(256) void scan_bsum(const int* __restrict__ bsum,
                                                 int* __restrict__ bpre,
                                                 int* __restrict__ offs) {
    __shared__ int sh[256];
    int t = threadIdx.x;
    int v = (t < SCAN_B) ? bsum[t] : 0;
    sh[t] = v;
    __syncthreads();
#pragma unroll
    for (int off = 1; off < 256; off <<= 1) {
        int u = (t >= off) ? sh[t - off] : 0;
        __syncthreads();
        sh[t] += u;
        __syncthreads();
    }
    if (t < SCAN_B) bpre[t] = sh[t] - v;
    if (t == SCAN_B - 1) offs[N_NODES] = sh[t];
}

__global__ __launch_bounds__(256) void block_scan(const int* __restrict__ counts,
                                                  const int* __restrict__ bpre,
                                                  int* __restrict__ offs,
                                                  int* __restrict__ cursor) {
    __shared__ int sh[256];
    int t = threadIdx.x;
    int i = blockIdx.x * 256 + t;
    int c = (i < N_NODES) ? counts[i] : 0;
    sh[t] = c;
    __syncthreads();
#pragma unroll
    for (int off = 1; off < 256; off <<= 1) {
        int u = (t >= off) ? sh[t - off] : 0;
        __syncthreads();
        sh[t] += u;
        __syncthreads();
    }
    if (i < N_NODES) {
        int e = bpre[blockIdx.x] + sh[t] - c;
        offs[i] = e;
        cursor[i] = e;
    }
}

__global__ void scatter_kernel(const int* __restrict__ src, const int* __restrict__ dst, int n_e,
                               int* __restrict__ cursor, int* __restrict__ csr_src) {
    int e = blockIdx.x * blockDim.x + threadIdx.x;
    if (e >= n_e) return;
    int d = dst[e];
    int pos = atomicAdd(&cursor[d], 1);
    csr_src[pos] = src[e];
}

// ---------------- graph boundary detection ----------------
__global__ void init_start(int* __restrict__ start) {
    int i = threadIdx.x;
    if (i < N_GRAPHS + 1) start[i] = N_NODES;
}

__global__ void find_start(const int* __restrict__ batch, int* __restrict__ start) {
    int i = blockIdx.x * blockDim.x + threadIdx.x;
    if (i >= N_NODES) return;
    int b = batch[i];
    if (i == 0) {
        start[b] = 0;
    } else {
        int pb = batch[i - 1];
        if (pb != b) start[b] = i;
    }
}

__global__ void fix_start(int* __restrict__ start) {
    if (threadIdx.x == 0) {
        for (int g = N_GRAPHS - 1; g >= 0; --g)
            if (start[g] == N_NODES) start[g] = start[g + 1];
    }
}

// ---------------- W fragment packing (split-f16) ----------------
__global__ void pack_w3(const float* __restrict__ W0, const float* __restrict__ W1,
                        const float* __restrict__ W2,
                        _Float16* __restrict__ Wh0, _Float16* __restrict__ Wl0,
                        _Float16* __restrict__ Wh1, _Float16* __restrict__ Wl1,
                        _Float16* __restrict__ Wh2, _Float16* __restrict__ Wl2) {
    int layer = blockIdx.x >> 3;
    const float* W = layer == 0 ? W0 : (layer == 1 ? W1 : W2);
    _Float16* Wh = layer == 0 ? Wh0 : (layer == 1 ? Wh1 : Wh2);
    _Float16* Wl = layer == 0 ? Wl0 : (layer == 1 ? Wl1 : Wl2);
    int t = (blockIdx.x & 7) * 256 + threadIdx.x;
    int lane = t & 63;
    int nt = (t >> 6) & 7;
    int kt = t >> 9;
    int n = nt * 16 + (lane & 15);
    int kbase = kt * 32 + (lane >> 4) * 8;
#pragma unroll
    for (int j = 0; j < 8; ++j) {
        float w = W[(size_t)(kbase + j) * 128 + n];
        _Float16 h = (_Float16)w;
        float r = w - (float)h;
        size_t idx = (size_t)t * 8 + j;
        Wh[idx] = h;
        Wl[idx] = (_Float16)r;
    }
}

// ---------------- MFMA GEMM + fused alpha; H written in slice-major layout ----------------
// Hs[slice][node][16] with slice = c>>4
__global__ __launch_bounds__(256) void gemm_mfma(const float* __restrict__ X,
                                                 const _Float16* __restrict__ Wh,
                                                 const _Float16* __restrict__ Wl,
                                                 const float* __restrict__ a_s,
                                                 const float* __restrict__ a_d,
                                                 float* __restrict__ Hs,
                                                 float* __restrict__ AS,
                                                 float* __restrict__ AD) {
    int t = threadIdx.x;
    int wave = t >> 6, lane = t & 63;
    int m15 = lane & 15, quad = lane >> 4;
    int rowbase = blockIdx.x * 64 + wave * 16;
    int arow = rowbase + m15;
    bool arow_ok = arow < N_NODES;

    f32x4 acc[8];
#pragma unroll
    for (int nt = 0; nt < 8; ++nt) acc[nt] = (f32x4){0.f, 0.f, 0.f, 0.f};

    const float* xrow = X + (size_t)arow * 128 + quad * 8;
#pragma unroll
    for (int kt = 0; kt < 4; ++kt) {
        f32x4 a0 = (f32x4){0.f, 0.f, 0.f, 0.f};
        f32x4 a1 = (f32x4){0.f, 0.f, 0.f, 0.f};
        if (arow_ok) {
            a0 = *(const f32x4*)(xrow + kt * 32);
            a1 = *(const f32x4*)(xrow + kt * 32 + 4);
        }
        half8 ah, al;
#pragma unroll
        for (int j = 0; j < 8; ++j) {
            float f = (j < 4) ? a0[j] : a1[j - 4];
            _Float16 h = (_Float16)f;
            ah[j] = h;
            al[j] = (_Float16)(f - (float)h);
        }
#pragma unroll
        for (int nt = 0; nt < 8; ++nt) {
            size_t fidx = ((size_t)((kt * 8 + nt) * 64 + lane)) * 8;
            half8 bh = *(const half8*)(Wh + fidx);
            half8 bl = *(const half8*)(Wl + fidx);
            acc[nt] = __builtin_amdgcn_mfma_f32_16x16x32_f16(ah, bh, acc[nt], 0, 0, 0);
            acc[nt] = __builtin_amdgcn_mfma_f32_16x16x32_f16(ah, bl, acc[nt], 0, 0, 0);
            acc[nt] = __builtin_amdgcn_mfma_f32_16x16x32_f16(al, bh, acc[nt], 0, 0, 0);
        }
    }

    float as_acc[4] = {0.f, 0.f, 0.f, 0.f};
    float ad_acc[4] = {0.f, 0.f, 0.f, 0.f};
#pragma unroll
    for (int nt = 0; nt < 8; ++nt) {
        int c = nt * 16 + m15;
        float cas = a_s[c];
        float cad = a_d[c];
#pragma unroll
        for (int reg = 0; reg < 4; ++reg) {
            float v = acc[nt][reg];
            as_acc[reg] += v * cas;
            ad_acc[reg] += v * cad;
            int gr = rowbase + quad * 4 + reg;
            if (gr < N_NODES)
                Hs[(size_t)nt * (N_NODES * 16) + (size_t)gr * 16 + m15] = v;
        }
    }
#pragma unroll
    for (int off = 1; off < 16; off <<= 1) {
#pragma unroll
        for (int reg = 0; reg < 4; ++reg) {
            as_acc[reg] += __shfl_xor(as_acc[reg], off);
            ad_acc[reg] += __shfl_xor(ad_acc[reg], off);
        }
    }
    if (m15 == 0) {
#pragma unroll
        for (int reg = 0; reg < 4; ++reg) {
            int gr = rowbase + quad * 4 + reg;
            if (gr < N_NODES) { AS[gr] = as_acc[reg]; AD[gr] = ad_acc[reg]; }
        }
    }
}

// ---------------- softmax coefs: one wave per node ----------------
// Writes normalized pcoef[e] (CSR order) and pself[n]; inv folded in.
__global__ __launch_bounds__(256) void coef_kernel(const float* __restrict__ AS,
                                                   const float* __restrict__ AD,
                                                   const int* __restrict__ offs,
                                                   const int* __restrict__ csr_src,
                                                   float* __restrict__ pcoef,
                                                   float* __restrict__ pself) {
    int node = blockIdx.x * 4 + (threadIdx.x >> 6);
    if (node >= N_NODES) return;
    int lane = threadIdx.x & 63;
    int beg = offs[node], end = offs[node + 1];
    int deg = end - beg;
    float ad = AD[node];
    float eself = lrelu(AS[node] + ad);

    if (deg <= 64) {
        float ev = -INFINITY;
        if (lane < deg) ev = lrelu(AS[csr_src[beg + lane]] + ad);
        float m = ev;
#pragma unroll
        for (int off = 32; off; off >>= 1) m = fmaxf(m, __shfl_xor(m, off));
        m = fmaxf(m, eself);
        float p = (lane < deg) ? expf(ev - m) : 0.f;
        float ssum = p;
#pragma unroll
        for (int off = 32; off; off >>= 1) ssum += __shfl_xor(ssum, off);
        float ps = expf(eself - m);
        float inv = 1.f / (ssum + ps + 1e-16f);
        if (lane < deg) pcoef[beg + lane] = p * inv;
        if (lane == 0) pself[node] = ps * inv;
    } else {
        float mym = -INFINITY;
        for (int i = beg + lane; i < end; i += 64)
            mym = fmaxf(mym, lrelu(AS[csr_src[i]] + ad));
#pragma unroll
        for (int off = 32; off; off >>= 1) mym = fmaxf(mym, __shfl_xor(mym, off));
        float m = fmaxf(mym, eself);
        float ssum = 0.f;
        for (int i = beg + lane; i < end; i += 64)
            ssum += expf(lrelu(AS[csr_src[i]] + ad) - m);
#pragma unroll
        for (int off = 32; off; off >>= 1) ssum += __shfl_xor(ssum, off);
        float ps = expf(eself - m);
        float inv = 1.f / (ssum + ps + 1e-16f);
        for (int i = beg + lane; i < end; i += 64)
            pcoef[i] = expf(lrelu(AS[csr_src[i]] + ad) - m) * inv;
        if (lane == 0) pself[node] = ps * inv;
    }
}

// ---------------- sliced gather: slice = blockIdx & 7 -> XCD-affine L2 residency ----------------
// Hs[slice][node][16]; working set per slice = 3.2 MB (line-pure) < 4 MB per-XCD L2.
__global__ __launch_bounds__(256) void gather_kernel(const float* __restrict__ Hs,
                                                     const float* __restrict__ pcoef,
                                                     const float* __restrict__ pself,
                                                     const int* __restrict__ offs,
                                                     const int* __restrict__ csr_src,
                                                     const float* __restrict__ bias,
                                                     float* __restrict__ OUT) {
    int slice = blockIdx.x & 7;
    int chunk = blockIdx.x >> 3;
    int wave = threadIdx.x >> 6, lane = threadIdx.x & 63;
    int q = lane >> 4, ch = lane & 15;
    const float* Hsl = Hs + (size_t)slice * (N_NODES * 16);
    float b = bias[slice * 16 + ch];

    int nbeg = chunk * NPB + wave * (NPB / 4);
    int nend = nbeg + NPB / 4;
    if (nend > N_NODES) nend = N_NODES;

    for (int n = nbeg; n < nend; ++n) {
        int beg = offs[n], end = offs[n + 1];
        float acc = 0.f;
        for (int e = beg + q; e < end; e += 4) {
            int s = csr_src[e];
            float c = pcoef[e];
            acc = fmaf(c, Hsl[(size_t)s * 16 + ch], acc);
        }
        if (q == 0) acc = fmaf(pself[n], Hsl[(size_t)n * 16 + ch], acc);
        acc += __shfl_xor(acc, 16);
        acc += __shfl_xor(acc, 32);
        if (q == 0) {
            float o = acc + b;
            o = o > 0.f ? o : expm1f(o);
            OUT[(size_t)n * 128 + slice * 16 + ch] = o;
        }
    }
}

// ---------------- global mean pool: 2-phase ----------------
__global__ __launch_bounds__(128) void pool_partial(const float* __restrict__ F,
                                                    const int* __restrict__ start,
                                                    float* __restrict__ partial) {
    int b = blockIdx.x;
    int g = b >> 4, sub = b & 15;
    int c = threadIdx.x;
    int s0 = start[g], e0 = start[g + 1];
    float acc = 0.f;
    for (int i = s0 + sub; i < e0; i += 16) acc += F[(size_t)i * 128 + c];
    partial[(size_t)b * 128 + c] = acc;
}

__global__ __launch_bounds__(128) void pool_final(const float* __restrict__ partial,
                                                  const int* __restrict__ start,
                                                  float* __restrict__ out) {
    int g = blockIdx.x;
    int c = threadIdx.x;
    float v = 0.f;
#pragma unroll
    for (int u = 0; u < 16; ++u) v += partial[(size_t)(g * 16 + u) * 128 + c];
    int cnt = start[g + 1] - start[g];
    out[(size_t)g * 128 + c] = v / (float)(cnt > 1 ? cnt : 1);
}

extern "C" void kernel_launch(void* const* d_in, const int* in_sizes, int n_in,
                              void* d_out, int out_size, void* d_ws, size_t ws_size,
                              hipStream_t stream) {
    const float* x = (const float*)d_in[0];
    const int* edge_index = (const int*)d_in[1];
    const int* batch = (const int*)d_in[2];
    const float* W[3]   = {(const float*)d_in[3], (const float*)d_in[7], (const float*)d_in[11]};
    const float* avs[3] = {(const float*)d_in[4], (const float*)d_in[8], (const float*)d_in[12]};
    const float* avd[3] = {(const float*)d_in[5], (const float*)d_in[9], (const float*)d_in[13]};
    const float* bb[3]  = {(const float*)d_in[6], (const float*)d_in[10], (const float*)d_in[14]};
    int E0 = in_sizes[1] / 2;
    const int* esrc = edge_index;
    const int* edst = edge_index + E0;

    char* p = (char*)d_ws;
    auto alloc = [&](size_t bytes) -> void* {
        void* q = (void*)p;
        p += (bytes + 255) & ~(size_t)255;
        return q;
    };
    int* counts   = (int*)alloc((size_t)N_NODES * 4);
    int* offs     = (int*)alloc((size_t)(N_NODES + 1) * 4);
    int* cursor   = (int*)alloc((size_t)N_NODES * 4);
    int* csr_src  = (int*)alloc((size_t)E0 * 4);
    int* start    = (int*)alloc((N_GRAPHS + 1) * 4);
    int* bsum     = (int*)alloc(SCAN_B * 4);
    int* bpre     = (int*)alloc(SCAN_B * 4);
    float* AS     = (float*)alloc((size_t)N_NODES * 4);
    float* AD     = (float*)alloc((size_t)N_NODES * 4);
    float* pcoef  = (float*)alloc((size_t)E0 * 4);
    float* pself  = (float*)alloc((size_t)N_NODES * 4);
    float* Hbuf   = (float*)alloc((size_t)N_NODES * HID * 4);  // slice-major
    float* FA     = (float*)alloc((size_t)N_NODES * HID * 4);
    float* FB     = (float*)alloc((size_t)N_NODES * HID * 4);
    float* partial = (float*)alloc((size_t)N_GRAPHS * 16 * 128 * 4);
    _Float16* Wh[3], *Wl[3];
    for (int l = 0; l < 3; ++l) {
        Wh[l] = (_Float16*)alloc(16384 * 2);
        Wl[l] = (_Float16*)alloc(16384 * 2);
    }

    // CSR build
    hipMemsetAsync(counts, 0, (size_t)N_NODES * 4, stream);
    count_kernel<<<(E0 + 255) / 256, 256, 0, stream>>>(edst, E0, counts);
    block_reduce<<<SCAN_B, 256, 0, stream>>>(counts, bsum);
    scan_bsum<<<1, 256, 0, stream>>>(bsum, bpre, offs);
    block_scan<<<SCAN_B, 256, 0, stream>>>(counts, bpre, offs, cursor);
    scatter_kernel<<<(E0 + 255) / 256, 256, 0, stream>>>(esrc, edst, E0, cursor, csr_src);

    // graph boundaries
    init_start<<<1, 128, 0, stream>>>(start);
    find_start<<<(N_NODES + 255) / 256, 256, 0, stream>>>(batch, start);
    fix_start<<<1, 64, 0, stream>>>(start);

    // W fragment packing
    pack_w3<<<24, 256, 0, stream>>>(W[0], W[1], W[2], Wh[0], Wl[0], Wh[1], Wl[1], Wh[2], Wl[2]);

    // 3 GAT layers
    const int gather_blocks = ((N_NODES + NPB - 1) / NPB) * 8;
    const float* cur = x;
    float* feat[2] = {FA, FB};
    for (int l = 0; l < 3; ++l) {
        gemm_mfma<<<(N_NODES + 63) / 64, 256, 0, stream>>>(cur, Wh[l], Wl[l], avs[l], avd[l],
                                                           Hbuf, AS, AD);
        coef_kernel<<<(N_NODES + 3) / 4, 256, 0, stream>>>(AS, AD, offs, csr_src, pcoef, pself);
        float* nxt = feat[l & 1];
        gather_kernel<<<gather_blocks, 256, 0, stream>>>(Hbuf, pcoef, pself, offs, csr_src,
                                                         bb[l], nxt);
        cur = nxt;
    }

    // global mean pool (2-phase)
    pool_partial<<<N_GRAPHS * 16, 128, 0, stream>>>(cur, start, partial);
    pool_final<<<N_GRAPHS, 128, 0, stream>>>(partial, start, (float*)d_out);
}

// Round 6
// 387.567 us; speedup vs baseline: 1.9612x; 1.9612x over previous
//
#include <hip/hip_runtime.h>
#include <math.h>

#define N_NODES 50000
#define N_GRAPHS 64
#define HID 128
#define SCAN_B 196  // ceil(50000/256)

typedef _Float16 half8 __attribute__((ext_vector_type(8)));
typedef _Float16 half4v __attribute__((ext_vector_type(4)));
typedef float f32x4 __attribute__((ext_vector_type(4)));

__device__ __forceinline__ float lrelu(float e) { return e > 0.f ? e : 0.2f * e; }

// ---------------- CSR build ----------------
__global__ void count_kernel(const int* __restrict__ dst, int n_e, int* __restrict__ counts) {
    int e = blockIdx.x * blockDim.x + threadIdx.x;
    if (e < n_e) atomicAdd(&counts[dst[e]], 1);
}

__global__ __launch_bounds__(256) void block_reduce(const int* __restrict__ counts,
                                                    int* __restrict__ bsum) {
    __shared__ int red[256];
    int t = threadIdx.x;
    int i = blockIdx.x * 256 + t;
    red[t] = (i < N_NODES) ? counts[i] : 0;
    __syncthreads();
#pragma unroll
    for (int off = 128; off; off >>= 1) {
        if (t < off) red[t] += red[t + off];
        __syncthreads();
    }
    if (t == 0) bsum[blockIdx.x] = red[0];
}

__global__ __launch_bounds__(256) void scan_bsum(const int* __restrict__ bsum,
                                                 int* __restrict__ bpre,
                                                 int* __restrict__ offs) {
    __shared__ int sh[256];
    int t = threadIdx.x;
    int v = (t < SCAN_B) ? bsum[t] : 0;
    sh[t] = v;
    __syncthreads();
#pragma unroll
    for (int off = 1; off < 256; off <<= 1) {
        int u = (t >= off) ? sh[t - off] : 0;
        __syncthreads();
        sh[t] += u;
        __syncthreads();
    }
    if (t < SCAN_B) bpre[t] = sh[t] - v;
    if (t == SCAN_B - 1) offs[N_NODES] = sh[t];
}

__global__ __launch_bounds__(256) void block_scan(const int* __restrict__ counts,
                                                  const int* __restrict__ bpre,
                                                  int* __restrict__ offs,
                                                  int* __restrict__ cursor) {
    __shared__ int sh[256];
    int t = threadIdx.x;
    int i = blockIdx.x * 256 + t;
    int c = (i < N_NODES) ? counts[i] : 0;
    sh[t] = c;
    __syncthreads();
#pragma unroll
    for (int off = 1; off < 256; off <<= 1) {
        int u = (t >= off) ? sh[t - off] : 0;
        __syncthreads();
        sh[t] += u;
        __syncthreads();
    }
    if (i < N_NODES) {
        int e = bpre[blockIdx.x] + sh[t] - c;
        offs[i] = e;
        cursor[i] = e;
    }
}

__global__ void scatter_kernel(const int* __restrict__ src, const int* __restrict__ dst, int n_e,
                               int* __restrict__ cursor, int* __restrict__ csr_src) {
    int e = blockIdx.x * blockDim.x + threadIdx.x;
    if (e >= n_e) return;
    int d = dst[e];
    int pos = atomicAdd(&cursor[d], 1);
    csr_src[pos] = src[e];
}

// ---------------- graph boundary detection ----------------
__global__ void init_start(int* __restrict__ start) {
    int i = threadIdx.x;
    if (i < N_GRAPHS + 1) start[i] = N_NODES;
}

__global__ void find_start(const int* __restrict__ batch, int* __restrict__ start) {
    int i = blockIdx.x * blockDim.x + threadIdx.x;
    if (i >= N_NODES) return;
    int b = batch[i];
    if (i == 0) {
        start[b] = 0;
    } else {
        int pb = batch[i - 1];
        if (pb != b) start[b] = i;
    }
}

__global__ void fix_start(int* __restrict__ start) {
    if (threadIdx.x == 0) {
        for (int g = N_GRAPHS - 1; g >= 0; --g)
            if (start[g] == N_NODES) start[g] = start[g + 1];
    }
}

// ---------------- W fragment packing (split-f16) ----------------
__global__ void pack_w3(const float* __restrict__ W0, const float* __restrict__ W1,
                        const float* __restrict__ W2,
                        _Float16* __restrict__ Wh0, _Float16* __restrict__ Wl0,
                        _Float16* __restrict__ Wh1, _Float16* __restrict__ Wl1,
                        _Float16* __restrict__ Wh2, _Float16* __restrict__ Wl2) {
    int layer = blockIdx.x >> 3;
    const float* W = layer == 0 ? W0 : (layer == 1 ? W1 : W2);
    _Float16* Wh = layer == 0 ? Wh0 : (layer == 1 ? Wh1 : Wh2);
    _Float16* Wl = layer == 0 ? Wl0 : (layer == 1 ? Wl1 : Wl2);
    int t = (blockIdx.x & 7) * 256 + threadIdx.x;
    int lane = t & 63;
    int nt = (t >> 6) & 7;
    int kt = t >> 9;
    int n = nt * 16 + (lane & 15);
    int kbase = kt * 32 + (lane >> 4) * 8;
#pragma unroll
    for (int j = 0; j < 8; ++j) {
        float w = W[(size_t)(kbase + j) * 128 + n];
        _Float16 h = (_Float16)w;
        float r = w - (float)h;
        size_t idx = (size_t)t * 8 + j;
        Wh[idx] = h;
        Wl[idx] = (_Float16)r;
    }
}

// ---------------- MFMA GEMM + fused alpha; H stored fp16 row-major for the gather ----------------
// Alphas computed from fp32 accumulators (accurate); H16 is only used for the weighted gather.
__global__ __launch_bounds__(256) void gemm_mfma(const float* __restrict__ X,
                                                 const _Float16* __restrict__ Wh,
                                                 const _Float16* __restrict__ Wl,
                                                 const float* __restrict__ a_s,
                                                 const float* __restrict__ a_d,
                                                 _Float16* __restrict__ H16,
                                                 float* __restrict__ AS,
                                                 float* __restrict__ AD) {
    int t = threadIdx.x;
    int wave = t >> 6, lane = t & 63;
    int m15 = lane & 15, quad = lane >> 4;
    int rowbase = blockIdx.x * 64 + wave * 16;
    int arow = rowbase + m15;
    bool arow_ok = arow < N_NODES;

    f32x4 acc[8];
#pragma unroll
    for (int nt = 0; nt < 8; ++nt) acc[nt] = (f32x4){0.f, 0.f, 0.f, 0.f};

    const float* xrow = X + (size_t)arow * 128 + quad * 8;
#pragma unroll
    for (int kt = 0; kt < 4; ++kt) {
        f32x4 a0 = (f32x4){0.f, 0.f, 0.f, 0.f};
        f32x4 a1 = (f32x4){0.f, 0.f, 0.f, 0.f};
        if (arow_ok) {
            a0 = *(const f32x4*)(xrow + kt * 32);
            a1 = *(const f32x4*)(xrow + kt * 32 + 4);
        }
        half8 ah, al;
#pragma unroll
        for (int j = 0; j < 8; ++j) {
            float f = (j < 4) ? a0[j] : a1[j - 4];
            _Float16 h = (_Float16)f;
            ah[j] = h;
            al[j] = (_Float16)(f - (float)h);
        }
#pragma unroll
        for (int nt = 0; nt < 8; ++nt) {
            size_t fidx = ((size_t)((kt * 8 + nt) * 64 + lane)) * 8;
            half8 bh = *(const half8*)(Wh + fidx);
            half8 bl = *(const half8*)(Wl + fidx);
            acc[nt] = __builtin_amdgcn_mfma_f32_16x16x32_f16(ah, bh, acc[nt], 0, 0, 0);
            acc[nt] = __builtin_amdgcn_mfma_f32_16x16x32_f16(ah, bl, acc[nt], 0, 0, 0);
            acc[nt] = __builtin_amdgcn_mfma_f32_16x16x32_f16(al, bh, acc[nt], 0, 0, 0);
        }
    }

    float as_acc[4] = {0.f, 0.f, 0.f, 0.f};
    float ad_acc[4] = {0.f, 0.f, 0.f, 0.f};
#pragma unroll
    for (int nt = 0; nt < 8; ++nt) {
        int c = nt * 16 + m15;
        float cas = a_s[c];
        float cad = a_d[c];
#pragma unroll
        for (int reg = 0; reg < 4; ++reg) {
            float v = acc[nt][reg];
            as_acc[reg] += v * cas;
            ad_acc[reg] += v * cad;
            int gr = rowbase + quad * 4 + reg;
            if (gr < N_NODES) H16[(size_t)gr * 128 + c] = (_Float16)v;
        }
    }
#pragma unroll
    for (int off = 1; off < 16; off <<= 1) {
#pragma unroll
        for (int reg = 0; reg < 4; ++reg) {
            as_acc[reg] += __shfl_xor(as_acc[reg], off);
            ad_acc[reg] += __shfl_xor(ad_acc[reg], off);
        }
    }
    if (m15 == 0) {
#pragma unroll
        for (int reg = 0; reg < 4; ++reg) {
            int gr = rowbase + quad * 4 + reg;
            if (gr < N_NODES) { AS[gr] = as_acc[reg]; AD[gr] = ad_acc[reg]; }
        }
    }
}

// ---------------- softmax coefs: one wave per node (normalized, inv folded in) ----------------
__global__ __launch_bounds__(256) void coef_kernel(const float* __restrict__ AS,
                                                   const float* __restrict__ AD,
                                                   const int* __restrict__ offs,
                                                   const int* __restrict__ csr_src,
                                                   float* __restrict__ pcoef,
                                                   float* __restrict__ pself) {
    int node = blockIdx.x * 4 + (threadIdx.x >> 6);
    if (node >= N_NODES) return;
    int lane = threadIdx.x & 63;
    int beg = offs[node], end = offs[node + 1];
    int deg = end - beg;
    float ad = AD[node];
    float eself = lrelu(AS[node] + ad);

    if (deg <= 64) {
        float ev = -INFINITY;
        if (lane < deg) ev = lrelu(AS[csr_src[beg + lane]] + ad);
        float m = ev;
#pragma unroll
        for (int off = 32; off; off >>= 1) m = fmaxf(m, __shfl_xor(m, off));
        m = fmaxf(m, eself);
        float p = (lane < deg) ? expf(ev - m) : 0.f;
        float ssum = p;
#pragma unroll
        for (int off = 32; off; off >>= 1) ssum += __shfl_xor(ssum, off);
        float ps = expf(eself - m);
        float inv = 1.f / (ssum + ps + 1e-16f);
        if (lane < deg) pcoef[beg + lane] = p * inv;
        if (lane == 0) pself[node] = ps * inv;
    } else {
        float mym = -INFINITY;
        for (int i = beg + lane; i < end; i += 64)
            mym = fmaxf(mym, lrelu(AS[csr_src[i]] + ad));
#pragma unroll
        for (int off = 32; off; off >>= 1) mym = fmaxf(mym, __shfl_xor(mym, off));
        float m = fmaxf(mym, eself);
        float ssum = 0.f;
        for (int i = beg + lane; i < end; i += 64)
            ssum += expf(lrelu(AS[csr_src[i]] + ad) - m);
#pragma unroll
        for (int off = 32; off; off >>= 1) ssum += __shfl_xor(ssum, off);
        float ps = expf(eself - m);
        float inv = 1.f / (ssum + ps + 1e-16f);
        for (int i = beg + lane; i < end; i += 64)
            pcoef[i] = expf(lrelu(AS[csr_src[i]] + ad) - m) * inv;
        if (lane == 0) pself[node] = ps * inv;
    }
}

// ---------------- fp16 full-row gather: one wave per node ----------------
// Row = 128 fp16 = 256B = 32 lanes x 8B. Halves take even/odd edges (2 edges per VMEM instr);
// no shuffles in the loop (coefs prenormalized). fp32 accumulate, combine via shfl_xor(32).
__global__ __launch_bounds__(256) void gather_kernel(const _Float16* __restrict__ H16,
                                                     const float* __restrict__ pcoef,
                                                     const float* __restrict__ pself,
                                                     const int* __restrict__ offs,
                                                     const int* __restrict__ csr_src,
                                                     const float* __restrict__ bias,
                                                     float* __restrict__ OUT) {
    int node = blockIdx.x * 4 + (threadIdx.x >> 6);
    if (node >= N_NODES) return;
    int lane = threadIdx.x & 63;
    int half = lane >> 5, l32 = lane & 31;
    int beg = offs[node], end = offs[node + 1];
    const half4v* H4 = (const half4v*)H16;  // row = 32 half4

    f32x4 accA = (f32x4){0.f, 0.f, 0.f, 0.f};
    f32x4 accB = (f32x4){0.f, 0.f, 0.f, 0.f};

    int e = beg + half;
    for (; e + 2 < end; e += 4) {
        int s0 = csr_src[e];
        int s1 = csr_src[e + 2];
        float c0 = pcoef[e];
        float c1 = pcoef[e + 2];
        half4v h0 = H4[(size_t)s0 * 32 + l32];
        half4v h1 = H4[(size_t)s1 * 32 + l32];
        accA.x = fmaf(c0, (float)h0[0], accA.x);
        accA.y = fmaf(c0, (float)h0[1], accA.y);
        accA.z = fmaf(c0, (float)h0[2], accA.z);
        accA.w = fmaf(c0, (float)h0[3], accA.w);
        accB.x = fmaf(c1, (float)h1[0], accB.x);
        accB.y = fmaf(c1, (float)h1[1], accB.y);
        accB.z = fmaf(c1, (float)h1[2], accB.z);
        accB.w = fmaf(c1, (float)h1[3], accB.w);
    }
    if (e < end) {
        int s0 = csr_src[e];
        float c0 = pcoef[e];
        half4v h0 = H4[(size_t)s0 * 32 + l32];
        accA.x = fmaf(c0, (float)h0[0], accA.x);
        accA.y = fmaf(c0, (float)h0[1], accA.y);
        accA.z = fmaf(c0, (float)h0[2], accA.z);
        accA.w = fmaf(c0, (float)h0[3], accA.w);
    }

    f32x4 acc;
    acc.x = accA.x + accB.x;
    acc.y = accA.y + accB.y;
    acc.z = accA.z + accB.z;
    acc.w = accA.w + accB.w;
    acc.x += __shfl_xor(acc.x, 32);
    acc.y += __shfl_xor(acc.y, 32);
    acc.z += __shfl_xor(acc.z, 32);
    acc.w += __shfl_xor(acc.w, 32);

    if (half == 0) {
        float ps = pself[node];
        half4v hs = H4[(size_t)node * 32 + l32];
        acc.x = fmaf(ps, (float)hs[0], acc.x);
        acc.y = fmaf(ps, (float)hs[1], acc.y);
        acc.z = fmaf(ps, (float)hs[2], acc.z);
        acc.w = fmaf(ps, (float)hs[3], acc.w);
        f32x4 b4 = ((const f32x4*)bias)[l32];
        f32x4 o;
        o.x = acc.x + b4.x;
        o.y = acc.y + b4.y;
        o.z = acc.z + b4.z;
        o.w = acc.w + b4.w;
        o.x = o.x > 0.f ? o.x : expm1f(o.x);
        o.y = o.y > 0.f ? o.y : expm1f(o.y);
        o.z = o.z > 0.f ? o.z : expm1f(o.z);
        o.w = o.w > 0.f ? o.w : expm1f(o.w);
        ((f32x4*)OUT)[(size_t)node * 32 + l32] = o;
    }
}

// ---------------- global mean pool: 2-phase ----------------
__global__ __launch_bounds__(128) void pool_partial(const float* __restrict__ F,
                                                    const int* __restrict__ start,
                                                    float* __restrict__ partial) {
    int b = blockIdx.x;
    int g = b >> 4, sub = b & 15;
    int c = threadIdx.x;
    int s0 = start[g], e0 = start[g + 1];
    float acc = 0.f;
    for (int i = s0 + sub; i < e0; i += 16) acc += F[(size_t)i * 128 + c];
    partial[(size_t)b * 128 + c] = acc;
}

__global__ __launch_bounds__(128) void pool_final(const float* __restrict__ partial,
                                                  const int* __restrict__ start,
                                                  float* __restrict__ out) {
    int g = blockIdx.x;
    int c = threadIdx.x;
    float v = 0.f;
#pragma unroll
    for (int u = 0; u < 16; ++u) v += partial[(size_t)(g * 16 + u) * 128 + c];
    int cnt = start[g + 1] - start[g];
    out[(size_t)g * 128 + c] = v / (float)(cnt > 1 ? cnt : 1);
}

extern "C" void kernel_launch(void* const* d_in, const int* in_sizes, int n_in,
                              void* d_out, int out_size, void* d_ws, size_t ws_size,
                              hipStream_t stream) {
    const float* x = (const float*)d_in[0];
    const int* edge_index = (const int*)d_in[1];
    const int* batch = (const int*)d_in[2];
    const float* W[3]   = {(const float*)d_in[3], (const float*)d_in[7], (const float*)d_in[11]};
    const float* avs[3] = {(const float*)d_in[4], (const float*)d_in[8], (const float*)d_in[12]};
    const float* avd[3] = {(const float*)d_in[5], (const float*)d_in[9], (const float*)d_in[13]};
    const float* bb[3]  = {(const float*)d_in[6], (const float*)d_in[10], (const float*)d_in[14]};
    int E0 = in_sizes[1] / 2;
    const int* esrc = edge_index;
    const int* edst = edge_index + E0;

    char* p = (char*)d_ws;
    auto alloc = [&](size_t bytes) -> void* {
        void* q = (void*)p;
        p += (bytes + 255) & ~(size_t)255;
        return q;
    };
    int* counts   = (int*)alloc((size_t)N_NODES * 4);
    int* offs     = (int*)alloc((size_t)(N_NODES + 1) * 4);
    int* cursor   = (int*)alloc((size_t)N_NODES * 4);
    int* csr_src  = (int*)alloc((size_t)E0 * 4);
    int* start    = (int*)alloc((N_GRAPHS + 1) * 4);
    int* bsum     = (int*)alloc(SCAN_B * 4);
    int* bpre     = (int*)alloc(SCAN_B * 4);
    float* AS     = (float*)alloc((size_t)N_NODES * 4);
    float* AD     = (float*)alloc((size_t)N_NODES * 4);
    float* pcoef  = (float*)alloc((size_t)E0 * 4);
    float* pself  = (float*)alloc((size_t)N_NODES * 4);
    _Float16* H16 = (_Float16*)alloc((size_t)N_NODES * HID * 2);
    float* FA     = (float*)alloc((size_t)N_NODES * HID * 4);
    float* FB     = (float*)alloc((size_t)N_NODES * HID * 4);
    float* partial = (float*)alloc((size_t)N_GRAPHS * 16 * 128 * 4);
    _Float16* Wh[3], *Wl[3];
    for (int l = 0; l < 3; ++l) {
        Wh[l] = (_Float16*)alloc(16384 * 2);
        Wl[l] = (_Float16*)alloc(16384 * 2);
    }

    // CSR build
    hipMemsetAsync(counts, 0, (size_t)N_NODES * 4, stream);
    count_kernel<<<(E0 + 255) / 256, 256, 0, stream>>>(edst, E0, counts);
    block_reduce<<<SCAN_B, 256, 0, stream>>>(counts, bsum);
    scan_bsum<<<1, 256, 0, stream>>>(bsum, bpre, offs);
    block_scan<<<SCAN_B, 256, 0, stream>>>(counts, bpre, offs, cursor);
    scatter_kernel<<<(E0 + 255) / 256, 256, 0, stream>>>(esrc, edst, E0, cursor, csr_src);

    // graph boundaries
    init_start<<<1, 128, 0, stream>>>(start);
    find_start<<<(N_NODES + 255) / 256, 256, 0, stream>>>(batch, start);
    fix_start<<<1, 64, 0, stream>>>(start);

    // W fragment packing
    pack_w3<<<24, 256, 0, stream>>>(W[0], W[1], W[2], Wh[0], Wl[0], Wh[1], Wl[1], Wh[2], Wl[2]);

    // 3 GAT layers
    const float* cur = x;
    float* feat[2] = {FA, FB};
    for (int l = 0; l < 3; ++l) {
        gemm_mfma<<<(N_NODES + 63) / 64, 256, 0, stream>>>(cur, Wh[l], Wl[l], avs[l], avd[l],
                                                           H16, AS, AD);
        coef_kernel<<<(N_NODES + 3) / 4, 256, 0, stream>>>(AS, AD, offs, csr_src, pcoef, pself);
        float* nxt = feat[l & 1];
        gather_kernel<<<(N_NODES + 3) / 4, 256, 0, stream>>>(H16, pcoef, pself, offs, csr_src,
                                                             bb[l], nxt);
        cur = nxt;
    }

    // global mean pool (2-phase)
    pool_partial<<<N_GRAPHS * 16, 128, 0, stream>>>(cur, start, partial);
    pool_final<<<N_GRAPHS, 128, 0, stream>>>(partial, start, (float*)d_out);
}